// Round 1
// baseline (428.038 us; speedup 1.0000x reference)
//
#include <hip/hip_runtime.h>
#include <stdint.h>
#include <math.h>

typedef int v4i  __attribute__((ext_vector_type(4)));
typedef int v16i __attribute__((ext_vector_type(16)));

#define NIMG 16
#define NCH  256
#define HDIM 56
#define HW   3136          // 56*56
#define NPIX 50176         // 16*3136
#define PADH 58
#define NKT  72            // 2304/32
#define NCOT 8             // 256/32
#define WELEMS 589824      // 256*256*3*3

// workspace layout (bytes)
#define A0_OFF   0
#define A0_BYTES (16*58*58*256)          // 13,778,944 padded NHWC int8 acts
#define WP0_OFF  (A0_OFF + A0_BYTES)
#define WP_BYTES (NKT*NCOT*64*16)        // 589,824 packed weight frags
#define WP1_OFF  (WP0_OFF + WP_BYTES)
#define COEF_OFF (WP1_OFF + WP_BYTES)    // floats A0[256] B0[256] A1[256] B1[256] scale0 scale1
#define MAXW_OFF (COEF_OFF + 4352)       // 2 x u32
#define SUM1_OFF (MAXW_OFF + 32)         // 512 x u64

__global__ void init_small(unsigned* maxw, unsigned long long* sums) {
    int t = threadIdx.x;
    if (t < 2) maxw[t] = 0u;
    for (int i = t; i < 512; i += 256) sums[i] = 0ull;
}

// per-channel BN0 stats -> affine coeffs: y = x*A0[c] + B0[c]
__global__ __launch_bounds__(256) void bn0_stats(const float* __restrict__ X,
        const float* __restrict__ g, const float* __restrict__ b,
        float* __restrict__ A0, float* __restrict__ B0) {
    __shared__ double sh[512];
    int c = blockIdx.x, t = threadIdx.x;
    double s = 0.0, s2 = 0.0;
    for (int n = 0; n < NIMG; ++n) {
        const float* p = X + (size_t)(n * NCH + c) * HW;
        for (int i = t; i < HW; i += 256) { double v = (double)p[i]; s += v; s2 += v * v; }
    }
    sh[t] = s; sh[256 + t] = s2; __syncthreads();
    for (int o = 128; o > 0; o >>= 1) {
        if (t < o) { sh[t] += sh[t + o]; sh[256 + t] += sh[256 + t + o]; }
        __syncthreads();
    }
    if (t == 0) {
        double mean = sh[0] / (double)NPIX;
        double var  = sh[256] / (double)NPIX - mean * mean;
        float meanf = (float)mean, varf = (float)var;
        float rstd = (float)(1.0 / sqrt((double)varf + 1e-5));
        float gc = g[c], bc = b[c];
        A0[c] = rstd * gc;
        B0[c] = bc - meanf * rstd * gc;
    }
}

// quantize BN0(x) -> padded NHWC int8, one block per (n,h)
__global__ __launch_bounds__(256) void quant0(const float* __restrict__ X,
        const float* __restrict__ A0, const float* __restrict__ B0,
        int8_t* __restrict__ A) {
    __shared__ int8_t tile[56 * 256];
    int n = blockIdx.x / 56, h = blockIdx.x % 56;
    int c = threadIdx.x;
    float ac = A0[c], bc = B0[c];
    const float* p = X + (size_t)(n * NCH + c) * HW + h * 56;
    for (int w = 0; w < 56; ++w) {
        float y = fmaf(p[w], ac, bc);
        y = fminf(fmaxf(y, 0.f), 1.f);
        tile[w * 256 + c] = (int8_t)(int)rintf(y * 15.f);
    }
    __syncthreads();
    unsigned* dst = (unsigned*)(A + (((size_t)n * PADH + h + 1) * PADH + 1) * 256);
    const unsigned* src = (const unsigned*)tile;
    for (int i = threadIdx.x; i < 56 * 64; i += 256) dst[i] = src[i];
}

__global__ __launch_bounds__(256) void wmax(const float* __restrict__ Wt, unsigned* out) {
    __shared__ float sh[256];
    float m = 0.f;
    for (int i = blockIdx.x * 256 + threadIdx.x; i < WELEMS; i += gridDim.x * 256)
        m = fmaxf(m, fabsf(Wt[i]));
    sh[threadIdx.x] = m; __syncthreads();
    for (int o = 128; o > 0; o >>= 1) {
        if (threadIdx.x < o) sh[threadIdx.x] = fmaxf(sh[threadIdx.x], sh[threadIdx.x + o]);
        __syncthreads();
    }
    if (threadIdx.x == 0) atomicMax(out, __float_as_uint(sh[0]));
}

// quantize weights and scatter into per-lane MFMA fragment layout
// Wpack[kt][cot][lane][16] ; k = tap*256 + ci ; lane = (k%32/16)*32 + (o%32) ; byte j = k%16
__global__ __launch_bounds__(256) void wpack(const float* __restrict__ Wt,
        const unsigned* __restrict__ maxwBits, int8_t* __restrict__ dst,
        float* __restrict__ scaleOut) {
    float maxw = tanhf(__uint_as_float(*maxwBits));
    if (blockIdx.x == 0 && threadIdx.x == 0) *scaleOut = maxw / 225.f;
    float twoM = 2.f * maxw;
    for (int e = blockIdx.x * 256 + threadIdx.x; e < WELEMS; e += gridDim.x * 256) {
        int o = e / 2304, rem = e % 2304;
        int ci = rem / 9, tap = rem % 9;
        float t = tanhf(Wt[e]);
        float wn = t / twoM + 0.5f;
        int r = (int)rintf(wn * 15.f);
        int q = 2 * r - 15;
        int k = tap * 256 + ci;
        int kt = k >> 5, k5 = k & 31;
        int lane = ((k5 >> 4) << 5) | (o & 31);
        int j = k5 & 15;
        dst[((((size_t)kt * NCOT + (o >> 5)) * 64 + lane) << 4) | j] = (int8_t)q;
    }
}

// conv0: D[pixel][cout] = act * W ; acts are A-operand. Output raw int32 NHWC (into d_out scratch).
__global__ __launch_bounds__(256) void conv0_mfma(const int8_t* __restrict__ A,
        const v4i* __restrict__ Wp, int* __restrict__ Cout) {
    int tid = threadIdx.x;
    int lane = tid & 63, wave = tid >> 6;
    int mtile = blockIdx.x * 4 + wave;          // 0..1567 pixel tiles
    int cot = blockIdx.y;                       // 0..7
    int p = mtile * 32 + (lane & 31);
    int n = p / HW; int r2 = p % HW; int y = r2 / 56; int xx = r2 % 56;
    const int8_t* ab = A + ((((size_t)n * PADH + y + 1) * PADH) + (xx + 1)) * 256 + ((lane >> 5) << 4);
    const v4i* wp = Wp + cot * 64 + lane;
    v16i acc = {0,0,0,0,0,0,0,0,0,0,0,0,0,0,0,0};
    #pragma unroll
    for (int tap = 0; tap < 9; ++tap) {
        const int dy = tap / 3 - 1, dx = tap % 3 - 1;
        const int8_t* ap = ab + (dy * PADH + dx) * 256;
        #pragma unroll
        for (int kk = 0; kk < 8; ++kk) {
            v4i af = *(const v4i*)(ap + kk * 32);
            v4i wf = wp[(tap * 8 + kk) * (NCOT * 64)];
            acc = __builtin_amdgcn_mfma_i32_32x32x32_i8(af, wf, acc, 0, 0, 0);
        }
    }
    int co = (cot << 5) | (lane & 31);
    int prb = (lane >> 5) << 2;
    int* cp = Cout + (size_t)(mtile * 32) * 256 + co;
    #pragma unroll
    for (int r = 0; r < 16; ++r) {
        int prow = (r & 3) + ((r >> 2) << 3) + prb;
        cp[prow * 256] = acc[r];
    }
}

// exact int64 per-channel stats of conv0 output
__global__ __launch_bounds__(256) void bn1_stats(const int* __restrict__ Cin,
        unsigned long long* __restrict__ sums) {
    int t = threadIdx.x;
    long long s = 0, s2 = 0;
    const int* p = Cin + (size_t)blockIdx.x * 98 * 256 + t;
    for (int i = 0; i < 98; ++i) {
        long long v = (long long)p[i * 256];
        s += v; s2 += v * v;
    }
    atomicAdd(&sums[t], (unsigned long long)s);
    atomicAdd(&sums[256 + t], (unsigned long long)s2);
}

__global__ void bn1_finalize(const unsigned long long* __restrict__ sums,
        const float* __restrict__ g, const float* __restrict__ b,
        const float* __restrict__ scale0p, float* __restrict__ A1, float* __restrict__ B1) {
    int c = threadIdx.x;
    double sc0 = (double)*scale0p;
    double S  = (double)(long long)sums[c];
    double S2 = (double)(long long)sums[256 + c];
    double meanS = S / (double)NPIX;
    double varS  = S2 / (double)NPIX - meanS * meanS;
    float meanf = (float)(sc0 * meanS);
    float varf  = (float)(sc0 * sc0 * varS);
    float rstd = (float)(1.0 / sqrt((double)varf + 1e-5));
    float gc = g[c], bc = b[c];
    A1[c] = (float)(sc0 * (double)rstd * (double)gc);
    B1[c] = bc - meanf * rstd * gc;
}

// requantize conv0 output -> padded NHWC int8 (reuses act buffer; halo still zero)
__global__ __launch_bounds__(256) void quant1(const int* __restrict__ Cin,
        const float* __restrict__ A1, const float* __restrict__ B1,
        int8_t* __restrict__ A) {
    int idx = blockIdx.x * 256 + threadIdx.x;
    int e4 = idx * 4;
    if (e4 >= NPIX * 256) return;
    int p = e4 >> 8, c4 = e4 & 255;
    int n = p / HW, r2 = p % HW, y = r2 / 56, xx = r2 % 56;
    const int4 v = *(const int4*)(Cin + e4);
    int vv[4] = {v.x, v.y, v.z, v.w};
    uchar4 q;
    unsigned char qq[4];
    #pragma unroll
    for (int j = 0; j < 4; ++j) {
        float y1 = fmaf((float)vv[j], A1[c4 + j], B1[c4 + j]);
        y1 = fminf(fmaxf(y1, 0.f), 1.f);
        qq[j] = (unsigned char)(int)rintf(y1 * 15.f);
    }
    q.x = qq[0]; q.y = qq[1]; q.z = qq[2]; q.w = qq[3];
    size_t dst = (((size_t)n * PADH + y + 1) * PADH + xx + 1) * 256 + c4;
    *(uchar4*)(A + dst) = q;
}

// conv1: W is A-operand, acts are B-operand -> D[cout][pixel]; fused scale + shortcut, NCHW out.
__global__ __launch_bounds__(256) void conv1_mfma(const int8_t* __restrict__ A,
        const v4i* __restrict__ Wp, const float* __restrict__ scale1p,
        const float* __restrict__ Xin, float* __restrict__ Out) {
    int tid = threadIdx.x;
    int lane = tid & 63, wave = tid >> 6;
    int ptile = blockIdx.x;                      // 0..1567
    int cot = blockIdx.y * 4 + wave;             // 0..7
    int p = ptile * 32 + (lane & 31);
    int n = p / HW; int r2 = p % HW; int y = r2 / 56; int xx = r2 % 56;
    const int8_t* ab = A + ((((size_t)n * PADH + y + 1) * PADH) + (xx + 1)) * 256 + ((lane >> 5) << 4);
    const v4i* wp = Wp + cot * 64 + lane;
    v16i acc = {0,0,0,0,0,0,0,0,0,0,0,0,0,0,0,0};
    #pragma unroll
    for (int tap = 0; tap < 9; ++tap) {
        const int dy = tap / 3 - 1, dx = tap % 3 - 1;
        const int8_t* ap = ab + (dy * PADH + dx) * 256;
        #pragma unroll
        for (int kk = 0; kk < 8; ++kk) {
            v4i af = *(const v4i*)(ap + kk * 32);
            v4i wf = wp[(tap * 8 + kk) * (NCOT * 64)];
            acc = __builtin_amdgcn_mfma_i32_32x32x32_i8(wf, af, acc, 0, 0, 0);
        }
    }
    float s1 = *scale1p;
    int crb = (lane >> 5) << 2;
    size_t base = (size_t)n * NCH * HW + y * 56 + xx;
    #pragma unroll
    for (int r = 0; r < 16; ++r) {
        int cin = (r & 3) + ((r >> 2) << 3) + crb;
        int co = (cot << 5) + cin;
        size_t off = base + (size_t)co * HW;
        Out[off] = fmaf(s1, (float)acc[r], Xin[off]);
    }
}

extern "C" void kernel_launch(void* const* d_in, const int* in_sizes, int n_in,
                              void* d_out, int out_size, void* d_ws, size_t ws_size,
                              hipStream_t stream) {
    const float* x  = (const float*)d_in[0];
    const float* g0 = (const float*)d_in[1];
    const float* b0 = (const float*)d_in[2];
    const float* w0 = (const float*)d_in[3];
    const float* g1 = (const float*)d_in[4];
    const float* b1 = (const float*)d_in[5];
    const float* w1 = (const float*)d_in[6];
    float* out = (float*)d_out;

    char* ws = (char*)d_ws;
    int8_t* a0 = (int8_t*)(ws + A0_OFF);
    v4i* wp0 = (v4i*)(ws + WP0_OFF);
    v4i* wp1 = (v4i*)(ws + WP1_OFF);
    float* coef = (float*)(ws + COEF_OFF);
    float* A0c = coef;       float* B0c = coef + 256;
    float* A1c = coef + 512; float* B1c = coef + 768;
    float* scale0 = coef + 1024; float* scale1 = coef + 1025;
    unsigned* maxw = (unsigned*)(ws + MAXW_OFF);
    unsigned long long* sums = (unsigned long long*)(ws + SUM1_OFF);

    int* c0 = (int*)d_out;   // conv0 raw int32 sums live in d_out until conv1 overwrites it

    hipMemsetAsync(a0, 0, A0_BYTES, stream);
    init_small<<<1, 256, 0, stream>>>(maxw, sums);
    bn0_stats<<<256, 256, 0, stream>>>(x, g0, b0, A0c, B0c);
    quant0<<<896, 256, 0, stream>>>(x, A0c, B0c, a0);
    wmax<<<256, 256, 0, stream>>>(w0, maxw);
    wmax<<<256, 256, 0, stream>>>(w1, maxw + 1);
    wpack<<<128, 256, 0, stream>>>(w0, maxw, (int8_t*)wp0, scale0);
    wpack<<<128, 256, 0, stream>>>(w1, maxw + 1, (int8_t*)wp1, scale1);
    conv0_mfma<<<dim3(392, 8), 256, 0, stream>>>(a0, wp0, c0);
    bn1_stats<<<512, 256, 0, stream>>>(c0, sums);
    bn1_finalize<<<1, 256, 0, stream>>>(sums, g1, b1, scale0, A1c, B1c);
    quant1<<<12544, 256, 0, stream>>>(c0, A1c, B1c, a0);
    conv1_mfma<<<dim3(1568, 2), 256, 0, stream>>>(a0, wp1, scale1, x, out);
}

// Round 2
// 256.922 us; speedup vs baseline: 1.6660x; 1.6660x over previous
//
#include <hip/hip_runtime.h>
#include <stdint.h>
#include <math.h>

typedef int v4i  __attribute__((ext_vector_type(4)));
typedef int v16i __attribute__((ext_vector_type(16)));

#define NIMG 16
#define NCH  256
#define HW   3136          // 56*56
#define NPIX 50176         // 16*3136
#define PADH 58
#define NKT  72            // 2304/32
#define NCOT 8             // 256/32
#define WELEMS 589824      // 256*256*3*3

// workspace layout (bytes)
#define A0_OFF   0
#define A0_BYTES (16*58*58*256)          // padded NHWC int8 acts
#define WP0_OFF  (A0_OFF + A0_BYTES)
#define WP_BYTES (NKT*NCOT*64*16)        // 589,824 packed weight frags
#define WP1_OFF  (WP0_OFF + WP_BYTES)
#define COEF_OFF (WP1_OFF + WP_BYTES)    // floats A0[256] B0[256] A1[256] B1[256] scale0 scale1
#define MAXW_OFF (COEF_OFF + 4352)       // 2 x u32
#define SUM1_OFF (MAXW_OFF + 32)         // 512 x u64

typedef __attribute__((address_space(1))) const unsigned int gu32;
typedef __attribute__((address_space(3))) unsigned int lu32;
__device__ __forceinline__ void gll16(const void* g, void* l) {
    __builtin_amdgcn_global_load_lds((gu32*)g, (lu32*)l, 16, 0, 0);
}

__global__ void init_small(unsigned* maxw, unsigned long long* sums) {
    int t = threadIdx.x;
    if (t < 2) maxw[t] = 0u;
    for (int i = t; i < 512; i += 256) sums[i] = 0ull;
}

// per-channel BN0 stats -> affine coeffs: y = x*A0[c] + B0[c]
__global__ __launch_bounds__(256) void bn0_stats(const float* __restrict__ X,
        const float* __restrict__ g, const float* __restrict__ b,
        float* __restrict__ A0, float* __restrict__ B0) {
    __shared__ double sh[512];
    int c = blockIdx.x, t = threadIdx.x;
    double s = 0.0, s2 = 0.0;
    for (int n = 0; n < NIMG; ++n) {
        const float* p = X + (size_t)(n * NCH + c) * HW;
        for (int i = t; i < HW; i += 256) { double v = (double)p[i]; s += v; s2 += v * v; }
    }
    sh[t] = s; sh[256 + t] = s2; __syncthreads();
    for (int o = 128; o > 0; o >>= 1) {
        if (t < o) { sh[t] += sh[t + o]; sh[256 + t] += sh[256 + t + o]; }
        __syncthreads();
    }
    if (t == 0) {
        double mean = sh[0] / (double)NPIX;
        double var  = sh[256] / (double)NPIX - mean * mean;
        float meanf = (float)mean, varf = (float)var;
        float rstd = (float)(1.0 / sqrt((double)varf + 1e-5));
        float gc = g[c], bc = b[c];
        A0[c] = rstd * gc;
        B0[c] = bc - meanf * rstd * gc;
    }
}

// quantize BN0(x) -> padded NHWC int8 via LDS transpose; one block per (n,h)
__global__ __launch_bounds__(256) void quant0(const float* __restrict__ X,
        const float* __restrict__ A0, const float* __restrict__ B0,
        int8_t* __restrict__ Apad) {
    __shared__ int8_t tile[56 * 260];     // stride 260: bank stride 65 -> conflict-free
    int h = blockIdx.x, n = blockIdx.y;
    int tid = threadIdx.x;
    const float* src = X + (size_t)n * NCH * HW + h * 56;
    for (int i = tid; i < 256 * 56; i += 256) {
        int c = i / 56, w = i - c * 56;
        float y = fmaf(src[(size_t)c * HW + w], A0[c], B0[c]);
        y = fminf(fmaxf(y, 0.f), 1.f);
        tile[w * 260 + c] = (int8_t)(int)rintf(y * 15.f);
    }
    __syncthreads();
    unsigned* dst = (unsigned*)(Apad + (((size_t)n * PADH + h + 1) * PADH + 1) * 256);
    for (int i = tid; i < 56 * 64; i += 256) {
        int w = i >> 6, c4 = (i & 63) << 2;
        dst[w * 64 + (c4 >> 2)] = *(const unsigned*)&tile[w * 260 + c4];
    }
}

__global__ __launch_bounds__(256) void wmax(const float* __restrict__ Wt, unsigned* out) {
    __shared__ float sh[256];
    float m = 0.f;
    for (int i = blockIdx.x * 256 + threadIdx.x; i < WELEMS; i += gridDim.x * 256)
        m = fmaxf(m, fabsf(Wt[i]));
    sh[threadIdx.x] = m; __syncthreads();
    for (int o = 128; o > 0; o >>= 1) {
        if (threadIdx.x < o) sh[threadIdx.x] = fmaxf(sh[threadIdx.x], sh[threadIdx.x + o]);
        __syncthreads();
    }
    if (threadIdx.x == 0) atomicMax(out, __float_as_uint(sh[0]));
}

// quantize weights and scatter into per-lane MFMA fragment layout
// Wpack[kt][cot][lane][16] ; k = tap*256 + ci ; lane = (k%32/16)*32 + (o%32) ; byte j = k%16
__global__ __launch_bounds__(256) void wpack(const float* __restrict__ Wt,
        const unsigned* __restrict__ maxwBits, int8_t* __restrict__ dst,
        float* __restrict__ scaleOut) {
    float maxw = tanhf(__uint_as_float(*maxwBits));
    if (blockIdx.x == 0 && threadIdx.x == 0) *scaleOut = maxw / 225.f;
    float twoM = 2.f * maxw;
    for (int e = blockIdx.x * 256 + threadIdx.x; e < WELEMS; e += gridDim.x * 256) {
        int o = e / 2304, rem = e % 2304;
        int ci = rem / 9, tap = rem % 9;
        float t = tanhf(Wt[e]);
        float wn = t / twoM + 0.5f;
        int r = (int)rintf(wn * 15.f);
        int q = 2 * r - 15;
        int k = tap * 256 + ci;
        int kt = k >> 5, k5 = k & 31;
        int lane = ((k5 >> 4) << 5) | (o & 31);
        int j = k5 & 15;
        dst[((((size_t)kt * NCOT + (o >> 5)) * 64 + lane) << 4) | j] = (int8_t)q;
    }
}

// Tiled implicit-GEMM conv. Block: 4 waves, 2 image rows (128 px slots, 112 valid) x 256 couts.
// Acts staged once in LDS (transposed [ch-half][px], pad 233); weights double-buffered 8KB/K-step.
// Wave: P=4 px-tiles x C=2 cout-tiles -> 8 acc tiles, 6 LDS reads per 8 MFMA.
template<int CONV1>
__global__ __launch_bounds__(256, 2) void conv_mfma(const int8_t* __restrict__ A,
        const v4i* __restrict__ Wp, int* __restrict__ Cout,
        const float* __restrict__ scale1p, const float* __restrict__ Xin,
        float* __restrict__ Out) {
    __shared__ v4i actT[16 * 233];        // 59.6 KB
    __shared__ v4i wbuf[2][512];          // 2 x 8 KB
    int tid = threadIdx.x;
    int lane = tid & 63, wave = tid >> 6;
    int rp = blockIdx.x, n = blockIdx.y;
    int y0 = rp * 2;
    int l31 = lane & 31, half = lane >> 5;

    float s1 = 0.f;
    if (CONV1) s1 = *scale1p;

    // ---- act staging: padded rows y0..y0+3, 58 cols, 256 ch -> transposed LDS
    const int8_t* asrc = A + (((size_t)n * PADH + y0) * PADH) * 256;
    for (int i = tid; i < 4 * 58 * 16; i += 256) {
        int rr = i / (58 * 16);
        int rem = i - rr * (58 * 16);
        int px = rem >> 4, hh = rem & 15;
        v4i v = *(const v4i*)(asrc + ((size_t)rr * PADH + px) * 256 + hh * 16);
        actT[hh * 233 + rr * 58 + px] = v;
    }
    asm volatile("s_waitcnt vmcnt(0) lgkmcnt(0)" ::: "memory");

    // ---- stage W[0] into wbuf[0] (2 outstanding VMEM from here on)
    const char* wgb = (const char*)Wp;
    gll16(wgb + tid * 16, (char*)&wbuf[0][0] + tid * 16);
    gll16(wgb + 4096 + tid * 16, (char*)&wbuf[0][0] + 4096 + tid * 16);

    // per-lane act pixel indices for the 4 px-tiles
    int pidx[4];
    #pragma unroll
    for (int m = 0; m < 4; ++m) {
        int s = m * 32 + l31;
        int rr = s >> 6, col = s & 63;
        int xx = col < 56 ? col : 55;     // clamp invalid lanes to a safe LDS px
        pidx[m] = (rr + 1) * 58 + xx + 1;
    }
    int c0 = wave, c1 = wave + 4;

    v16i acc[8] = {};

    int kt = 0;
    #pragma unroll 1
    for (int dyi = 0; dyi < 3; ++dyi) {
        #pragma unroll
        for (int dxi = 0; dxi < 3; ++dxi) {
            int doff = dyi * 58 + dxi - 59;
            #pragma unroll
            for (int kk = 0; kk < 8; ++kk) {
                int ktn = kt + 1; if (ktn > 71) ktn = 71;
                char* dstb = (char*)&wbuf[ktn & 1][0];
                gll16(wgb + (size_t)ktn * 8192 + tid * 16, dstb + tid * 16);
                gll16(wgb + (size_t)ktn * 8192 + 4096 + tid * 16, dstb + 4096 + tid * 16);
                asm volatile("s_waitcnt vmcnt(2)" ::: "memory");
                __builtin_amdgcn_s_barrier();        // W[kt] staged by all waves
                const v4i* wb = &wbuf[kt & 1][0];
                int hb = (kk * 2 + half) * 233 + doff;
                v4i af0 = actT[hb + pidx[0]];
                v4i af1 = actT[hb + pidx[1]];
                v4i af2 = actT[hb + pidx[2]];
                v4i af3 = actT[hb + pidx[3]];
                v4i wf0 = wb[c0 * 64 + lane];
                v4i wf1 = wb[c1 * 64 + lane];
                asm volatile("s_waitcnt lgkmcnt(0)" ::: "memory");
                __builtin_amdgcn_sched_barrier(0);
                __builtin_amdgcn_s_barrier();        // reads retired -> next stage safe
                if (CONV1) {
                    acc[0] = __builtin_amdgcn_mfma_i32_32x32x32_i8(wf0, af0, acc[0], 0, 0, 0);
                    acc[1] = __builtin_amdgcn_mfma_i32_32x32x32_i8(wf0, af1, acc[1], 0, 0, 0);
                    acc[2] = __builtin_amdgcn_mfma_i32_32x32x32_i8(wf0, af2, acc[2], 0, 0, 0);
                    acc[3] = __builtin_amdgcn_mfma_i32_32x32x32_i8(wf0, af3, acc[3], 0, 0, 0);
                    acc[4] = __builtin_amdgcn_mfma_i32_32x32x32_i8(wf1, af0, acc[4], 0, 0, 0);
                    acc[5] = __builtin_amdgcn_mfma_i32_32x32x32_i8(wf1, af1, acc[5], 0, 0, 0);
                    acc[6] = __builtin_amdgcn_mfma_i32_32x32x32_i8(wf1, af2, acc[6], 0, 0, 0);
                    acc[7] = __builtin_amdgcn_mfma_i32_32x32x32_i8(wf1, af3, acc[7], 0, 0, 0);
                } else {
                    acc[0] = __builtin_amdgcn_mfma_i32_32x32x32_i8(af0, wf0, acc[0], 0, 0, 0);
                    acc[1] = __builtin_amdgcn_mfma_i32_32x32x32_i8(af1, wf0, acc[1], 0, 0, 0);
                    acc[2] = __builtin_amdgcn_mfma_i32_32x32x32_i8(af2, wf0, acc[2], 0, 0, 0);
                    acc[3] = __builtin_amdgcn_mfma_i32_32x32x32_i8(af3, wf0, acc[3], 0, 0, 0);
                    acc[4] = __builtin_amdgcn_mfma_i32_32x32x32_i8(af0, wf1, acc[4], 0, 0, 0);
                    acc[5] = __builtin_amdgcn_mfma_i32_32x32x32_i8(af1, wf1, acc[5], 0, 0, 0);
                    acc[6] = __builtin_amdgcn_mfma_i32_32x32x32_i8(af2, wf1, acc[6], 0, 0, 0);
                    acc[7] = __builtin_amdgcn_mfma_i32_32x32x32_i8(af3, wf1, acc[7], 0, 0, 0);
                }
                ++kt;
            }
        }
    }
    asm volatile("s_waitcnt vmcnt(0)" ::: "memory");  // drain the redundant final stage

    if (!CONV1) {
        int pbase = n * HW + y0 * 56;
        #pragma unroll
        for (int ci = 0; ci < 2; ++ci) {
            int co = (wave + ci * 4) * 32 + l31;
            #pragma unroll
            for (int m = 0; m < 4; ++m) {
                v16i a = acc[ci * 4 + m];
                #pragma unroll
                for (int r = 0; r < 16; ++r) {
                    int prow = (r & 3) + ((r >> 2) << 3) + (half << 2);
                    int s = m * 32 + prow;
                    int rr = s >> 6, col = s & 63;
                    if (col < 56)
                        Cout[(size_t)(pbase + rr * 56 + col) * 256 + co] = a[r];
                }
            }
        }
    } else {
        #pragma unroll
        for (int m = 0; m < 4; ++m) {
            int s = m * 32 + l31;
            int rr = s >> 6, col = s & 63;
            if (col < 56) {
                size_t boff = (size_t)n * NCH * HW + (size_t)(y0 + rr) * 56 + col;
                #pragma unroll
                for (int ci = 0; ci < 2; ++ci) {
                    v16i a = acc[ci * 4 + m];
                    #pragma unroll
                    for (int r = 0; r < 16; ++r) {
                        int prow = (r & 3) + ((r >> 2) << 3) + (half << 2);
                        int co = (wave + ci * 4) * 32 + prow;
                        size_t off = boff + (size_t)co * HW;
                        Out[off] = fmaf(s1, (float)a[r], Xin[off]);
                    }
                }
            }
        }
    }
}

// exact int64 per-channel stats of conv0 output
__global__ __launch_bounds__(256) void bn1_stats(const int* __restrict__ Cin,
        unsigned long long* __restrict__ sums) {
    int t = threadIdx.x;
    long long s = 0, s2 = 0;
    const int* p = Cin + (size_t)blockIdx.x * 98 * 256 + t;
    for (int i = 0; i < 98; ++i) {
        long long v = (long long)p[i * 256];
        s += v; s2 += v * v;
    }
    atomicAdd(&sums[t], (unsigned long long)s);
    atomicAdd(&sums[256 + t], (unsigned long long)s2);
}

__global__ void bn1_finalize(const unsigned long long* __restrict__ sums,
        const float* __restrict__ g, const float* __restrict__ b,
        const float* __restrict__ scale0p, float* __restrict__ A1, float* __restrict__ B1) {
    int c = threadIdx.x;
    double sc0 = (double)*scale0p;
    double S  = (double)(long long)sums[c];
    double S2 = (double)(long long)sums[256 + c];
    double meanS = S / (double)NPIX;
    double varS  = S2 / (double)NPIX - meanS * meanS;
    float meanf = (float)(sc0 * meanS);
    float varf  = (float)(sc0 * sc0 * varS);
    float rstd = (float)(1.0 / sqrt((double)varf + 1e-5));
    float gc = g[c], bc = b[c];
    A1[c] = (float)(sc0 * (double)rstd * (double)gc);
    B1[c] = bc - meanf * rstd * gc;
}

// requantize conv0 output -> padded NHWC int8 (reuses act buffer; halo still zero)
__global__ __launch_bounds__(256) void quant1(const int* __restrict__ Cin,
        const float* __restrict__ A1, const float* __restrict__ B1,
        int8_t* __restrict__ A) {
    int idx = blockIdx.x * 256 + threadIdx.x;
    int e4 = idx * 4;
    if (e4 >= NPIX * 256) return;
    int p = e4 >> 8, c4 = e4 & 255;
    int n = p / HW, r2 = p % HW, y = r2 / 56, xx = r2 % 56;
    const int4 v = *(const int4*)(Cin + e4);
    int vv[4] = {v.x, v.y, v.z, v.w};
    uchar4 q;
    unsigned char qq[4];
    #pragma unroll
    for (int j = 0; j < 4; ++j) {
        float y1 = fmaf((float)vv[j], A1[c4 + j], B1[c4 + j]);
        y1 = fminf(fmaxf(y1, 0.f), 1.f);
        qq[j] = (unsigned char)(int)rintf(y1 * 15.f);
    }
    q.x = qq[0]; q.y = qq[1]; q.z = qq[2]; q.w = qq[3];
    size_t dst = (((size_t)n * PADH + y + 1) * PADH + xx + 1) * 256 + c4;
    *(uchar4*)(A + dst) = q;
}

extern "C" void kernel_launch(void* const* d_in, const int* in_sizes, int n_in,
                              void* d_out, int out_size, void* d_ws, size_t ws_size,
                              hipStream_t stream) {
    const float* x  = (const float*)d_in[0];
    const float* g0 = (const float*)d_in[1];
    const float* b0 = (const float*)d_in[2];
    const float* w0 = (const float*)d_in[3];
    const float* g1 = (const float*)d_in[4];
    const float* b1 = (const float*)d_in[5];
    const float* w1 = (const float*)d_in[6];
    float* out = (float*)d_out;

    char* ws = (char*)d_ws;
    int8_t* a0 = (int8_t*)(ws + A0_OFF);
    v4i* wp0 = (v4i*)(ws + WP0_OFF);
    v4i* wp1 = (v4i*)(ws + WP1_OFF);
    float* coef = (float*)(ws + COEF_OFF);
    float* A0c = coef;       float* B0c = coef + 256;
    float* A1c = coef + 512; float* B1c = coef + 768;
    float* scale0 = coef + 1024; float* scale1 = coef + 1025;
    unsigned* maxw = (unsigned*)(ws + MAXW_OFF);
    unsigned long long* sums = (unsigned long long*)(ws + SUM1_OFF);

    int* c0 = (int*)d_out;   // conv0 raw int32 sums live in d_out until conv1 overwrites it

    hipMemsetAsync(a0, 0, A0_BYTES, stream);
    init_small<<<1, 256, 0, stream>>>(maxw, sums);
    bn0_stats<<<256, 256, 0, stream>>>(x, g0, b0, A0c, B0c);
    quant0<<<dim3(56, 16), 256, 0, stream>>>(x, A0c, B0c, a0);
    wmax<<<256, 256, 0, stream>>>(w0, maxw);
    wmax<<<256, 256, 0, stream>>>(w1, maxw + 1);
    wpack<<<128, 256, 0, stream>>>(w0, maxw, (int8_t*)wp0, scale0);
    wpack<<<128, 256, 0, stream>>>(w1, maxw + 1, (int8_t*)wp1, scale1);
    conv_mfma<0><<<dim3(28, 16), 256, 0, stream>>>(a0, wp0, c0, nullptr, nullptr, nullptr);
    bn1_stats<<<512, 256, 0, stream>>>(c0, sums);
    bn1_finalize<<<1, 256, 0, stream>>>(sums, g1, b1, scale0, A1c, B1c);
    quant1<<<12544, 256, 0, stream>>>(c0, A1c, B1c, a0);
    conv_mfma<1><<<dim3(28, 16), 256, 0, stream>>>(a0, wp1, nullptr, scale1, x, out);
}

// Round 3
// 192.986 us; speedup vs baseline: 2.2180x; 1.3313x over previous
//
#include <hip/hip_runtime.h>
#include <stdint.h>
#include <math.h>

typedef int v4i  __attribute__((ext_vector_type(4)));
typedef int v16i __attribute__((ext_vector_type(16)));

#define NIMG 16
#define NCH  256
#define HW   3136          // 56*56
#define NPIX 50176         // 16*3136
#define PADH 58
#define NKT  72            // 2304/32
#define NCOT 8             // 256/32
#define WELEMS 589824      // 256*256*3*3

// workspace layout (bytes)
#define A0_OFF   0
#define A0_BYTES (16*58*58*256)          // padded NHWC int8 acts
#define WP0_OFF  (A0_OFF + A0_BYTES)
#define WP_BYTES (NKT*NCOT*64*16)        // 589,824 packed weight frags
#define WP1_OFF  (WP0_OFF + WP_BYTES)
#define COEF_OFF (WP1_OFF + WP_BYTES)    // floats A0[256] B0[256] A1[256] B1[256] scale0 scale1
#define MAXW_OFF (COEF_OFF + 4352)       // 2 x u32
#define SUM1_OFF (MAXW_OFF + 32)         // 512 x u64
#define PART_OFF (SUM1_OFF + 4096)       // 4096 x double2 (bn0 per-plane partials)

typedef __attribute__((address_space(1))) const unsigned int gu32;
typedef __attribute__((address_space(3))) unsigned int lu32;
__device__ __forceinline__ void gll16(const void* g, void* l) {
    __builtin_amdgcn_global_load_lds((gu32*)g, (lu32*)l, 16, 0, 0);
}

__global__ void init_small(unsigned* maxw, unsigned long long* sums) {
    int t = threadIdx.x;
    if (t < 2) maxw[t] = 0u;
    for (int i = t; i < 512; i += 256) sums[i] = 0ull;
}

// bn0 stage 1: per-(n,c)-plane sum/sumsq in double, one block per plane
__global__ __launch_bounds__(256) void bn0_part(const float* __restrict__ X,
        double2* __restrict__ part) {
    int p = blockIdx.x;                    // n*256 + c
    const float4* src = (const float4*)(X + (size_t)p * HW);
    double s = 0.0, s2 = 0.0;
    for (int i = threadIdx.x; i < HW / 4; i += 256) {
        float4 v = src[i];
        s  += (double)v.x + (double)v.y + (double)v.z + (double)v.w;
        s2 += (double)v.x * (double)v.x + (double)v.y * (double)v.y
            + (double)v.z * (double)v.z + (double)v.w * (double)v.w;
    }
    #pragma unroll
    for (int off = 32; off; off >>= 1) {
        s  += __shfl_xor(s, off);
        s2 += __shfl_xor(s2, off);
    }
    __shared__ double sh[8];
    int wave = threadIdx.x >> 6, lane = threadIdx.x & 63;
    if (lane == 0) { sh[wave * 2] = s; sh[wave * 2 + 1] = s2; }
    __syncthreads();
    if (threadIdx.x == 0) {
        double2 o; o.x = sh[0] + sh[2] + sh[4] + sh[6];
        o.y = sh[1] + sh[3] + sh[5] + sh[7];
        part[p] = o;
    }
}

// bn0 stage 2: combine 16 planes per channel (fixed order), emit affine coeffs
__global__ void bn0_final(const double2* __restrict__ part,
        const float* __restrict__ g, const float* __restrict__ b,
        float* __restrict__ A0, float* __restrict__ B0) {
    int c = threadIdx.x;
    double s = 0.0, s2 = 0.0;
    for (int n = 0; n < NIMG; ++n) {
        double2 v = part[n * 256 + c];
        s += v.x; s2 += v.y;
    }
    double mean = s / (double)NPIX;
    double var  = s2 / (double)NPIX - mean * mean;
    float meanf = (float)mean, varf = (float)var;
    float rstd = (float)(1.0 / sqrt((double)varf + 1e-5));
    float gc = g[c], bc = b[c];
    A0[c] = rstd * gc;
    B0[c] = bc - meanf * rstd * gc;
}

// quantize BN0(x) -> padded NHWC int8 via LDS transpose; one block per (n,h)
__global__ __launch_bounds__(256) void quant0(const float* __restrict__ X,
        const float* __restrict__ A0, const float* __restrict__ B0,
        int8_t* __restrict__ Apad) {
    __shared__ int8_t tile[56 * 260];     // stride 260: conflict-free byte columns
    int h = blockIdx.x, n = blockIdx.y;
    int tid = threadIdx.x;
    const float4* src4 = (const float4*)X;
    for (int i = tid; i < 256 * 14; i += 256) {
        int c = i / 14, q = i - c * 14;
        float4 v = src4[((size_t)(n * 256 + c) * HW + h * 56) / 4 + q];
        float ac = A0[c], bc = B0[c];
        float vv[4] = {v.x, v.y, v.z, v.w};
        #pragma unroll
        for (int j = 0; j < 4; ++j) {
            float y = fmaf(vv[j], ac, bc);
            y = fminf(fmaxf(y, 0.f), 1.f);
            tile[(q * 4 + j) * 260 + c] = (int8_t)(int)rintf(y * 15.f);
        }
    }
    __syncthreads();
    unsigned* dst = (unsigned*)(Apad + (((size_t)n * PADH + h + 1) * PADH + 1) * 256);
    for (int i = tid; i < 56 * 64; i += 256) {
        int w = i >> 6, c4 = (i & 63) << 2;
        dst[w * 64 + (c4 >> 2)] = *(const unsigned*)&tile[w * 260 + c4];
    }
}

__global__ __launch_bounds__(256) void wmax(const float* __restrict__ Wt, unsigned* out) {
    __shared__ float sh[256];
    float m = 0.f;
    for (int i = blockIdx.x * 256 + threadIdx.x; i < WELEMS; i += gridDim.x * 256)
        m = fmaxf(m, fabsf(Wt[i]));
    sh[threadIdx.x] = m; __syncthreads();
    for (int o = 128; o > 0; o >>= 1) {
        if (threadIdx.x < o) sh[threadIdx.x] = fmaxf(sh[threadIdx.x], sh[threadIdx.x + o]);
        __syncthreads();
    }
    if (threadIdx.x == 0) atomicMax(out, __float_as_uint(sh[0]));
}

// quantize weights and scatter into per-lane MFMA fragment layout
// Wpack[kt][cot][lane][16] ; k = tap*256 + ci ; lane = (k%32/16)*32 + (o%32) ; byte j = k%16
__global__ __launch_bounds__(256) void wpack(const float* __restrict__ Wt,
        const unsigned* __restrict__ maxwBits, int8_t* __restrict__ dst,
        float* __restrict__ scaleOut) {
    float maxw = tanhf(__uint_as_float(*maxwBits));
    if (blockIdx.x == 0 && threadIdx.x == 0) *scaleOut = maxw / 225.f;
    float twoM = 2.f * maxw;
    for (int e = blockIdx.x * 256 + threadIdx.x; e < WELEMS; e += gridDim.x * 256) {
        int o = e / 2304, rem = e % 2304;
        int ci = rem / 9, tap = rem % 9;
        float t = tanhf(Wt[e]);
        float wn = t / twoM + 0.5f;
        int r = (int)rintf(wn * 15.f);
        int q = 2 * r - 15;
        int k = tap * 256 + ci;
        int kt = k >> 5, k5 = k & 31;
        int lane = ((k5 >> 4) << 5) | (o & 31);
        int j = k5 & 15;
        dst[((((size_t)kt * NCOT + (o >> 5)) * 64 + lane) << 4) | j] = (int8_t)q;
    }
}

// Tiled implicit-GEMM conv. Block: 4 waves, 2 image rows (128 px slots, 112 valid) x 256 couts.
// conv0 epilogue also accumulates exact per-channel int64 sum/sumsq (bn1 stats fused).
template<int CONV1>
__global__ __launch_bounds__(256, 2) void conv_mfma(const int8_t* __restrict__ A,
        const v4i* __restrict__ Wp, int* __restrict__ Cout,
        unsigned long long* __restrict__ sums,
        const float* __restrict__ scale1p, const float* __restrict__ Xin,
        float* __restrict__ Out) {
    __shared__ v4i actT[16 * 233];        // 59.6 KB
    __shared__ v4i wbuf[2][512];          // 2 x 8 KB
    int tid = threadIdx.x;
    int lane = tid & 63, wave = tid >> 6;
    int rp = blockIdx.x, n = blockIdx.y;
    int y0 = rp * 2;
    int l31 = lane & 31, half = lane >> 5;

    float s1 = 0.f;
    if (CONV1) s1 = *scale1p;

    // ---- act staging: padded rows y0..y0+3, 58 cols, 256 ch -> transposed LDS
    const int8_t* asrc = A + (((size_t)n * PADH + y0) * PADH) * 256;
    for (int i = tid; i < 4 * 58 * 16; i += 256) {
        int rr = i / (58 * 16);
        int rem = i - rr * (58 * 16);
        int px = rem >> 4, hh = rem & 15;
        v4i v = *(const v4i*)(asrc + ((size_t)rr * PADH + px) * 256 + hh * 16);
        actT[hh * 233 + rr * 58 + px] = v;
    }
    asm volatile("s_waitcnt vmcnt(0) lgkmcnt(0)" ::: "memory");

    // ---- stage W[0] into wbuf[0] (2 outstanding VMEM from here on)
    const char* wgb = (const char*)Wp;
    gll16(wgb + tid * 16, (char*)&wbuf[0][0] + tid * 16);
    gll16(wgb + 4096 + tid * 16, (char*)&wbuf[0][0] + 4096 + tid * 16);

    // per-lane act pixel indices for the 4 px-tiles
    int pidx[4];
    #pragma unroll
    for (int m = 0; m < 4; ++m) {
        int s = m * 32 + l31;
        int rr = s >> 6, col = s & 63;
        int xx = col < 56 ? col : 55;     // clamp invalid lanes to a safe LDS px
        pidx[m] = (rr + 1) * 58 + xx + 1;
    }
    int c0 = wave, c1 = wave + 4;

    v16i acc[8] = {};

    int kt = 0;
    #pragma unroll 1
    for (int dyi = 0; dyi < 3; ++dyi) {
        #pragma unroll
        for (int dxi = 0; dxi < 3; ++dxi) {
            int doff = dyi * 58 + dxi - 59;
            #pragma unroll
            for (int kk = 0; kk < 8; ++kk) {
                int ktn = kt + 1; if (ktn > 71) ktn = 71;
                char* dstb = (char*)&wbuf[ktn & 1][0];
                gll16(wgb + (size_t)ktn * 8192 + tid * 16, dstb + tid * 16);
                gll16(wgb + (size_t)ktn * 8192 + 4096 + tid * 16, dstb + 4096 + tid * 16);
                asm volatile("s_waitcnt vmcnt(2)" ::: "memory");
                __builtin_amdgcn_s_barrier();        // W[kt] staged by all waves
                const v4i* wb = &wbuf[kt & 1][0];
                int hb = (kk * 2 + half) * 233 + doff;
                v4i af0 = actT[hb + pidx[0]];
                v4i af1 = actT[hb + pidx[1]];
                v4i af2 = actT[hb + pidx[2]];
                v4i af3 = actT[hb + pidx[3]];
                v4i wf0 = wb[c0 * 64 + lane];
                v4i wf1 = wb[c1 * 64 + lane];
                asm volatile("s_waitcnt lgkmcnt(0)" ::: "memory");
                __builtin_amdgcn_sched_barrier(0);
                __builtin_amdgcn_s_barrier();        // reads retired -> next stage safe
                if (CONV1) {
                    acc[0] = __builtin_amdgcn_mfma_i32_32x32x32_i8(wf0, af0, acc[0], 0, 0, 0);
                    acc[1] = __builtin_amdgcn_mfma_i32_32x32x32_i8(wf0, af1, acc[1], 0, 0, 0);
                    acc[2] = __builtin_amdgcn_mfma_i32_32x32x32_i8(wf0, af2, acc[2], 0, 0, 0);
                    acc[3] = __builtin_amdgcn_mfma_i32_32x32x32_i8(wf0, af3, acc[3], 0, 0, 0);
                    acc[4] = __builtin_amdgcn_mfma_i32_32x32x32_i8(wf1, af0, acc[4], 0, 0, 0);
                    acc[5] = __builtin_amdgcn_mfma_i32_32x32x32_i8(wf1, af1, acc[5], 0, 0, 0);
                    acc[6] = __builtin_amdgcn_mfma_i32_32x32x32_i8(wf1, af2, acc[6], 0, 0, 0);
                    acc[7] = __builtin_amdgcn_mfma_i32_32x32x32_i8(wf1, af3, acc[7], 0, 0, 0);
                } else {
                    acc[0] = __builtin_amdgcn_mfma_i32_32x32x32_i8(af0, wf0, acc[0], 0, 0, 0);
                    acc[1] = __builtin_amdgcn_mfma_i32_32x32x32_i8(af1, wf0, acc[1], 0, 0, 0);
                    acc[2] = __builtin_amdgcn_mfma_i32_32x32x32_i8(af2, wf0, acc[2], 0, 0, 0);
                    acc[3] = __builtin_amdgcn_mfma_i32_32x32x32_i8(af3, wf0, acc[3], 0, 0, 0);
                    acc[4] = __builtin_amdgcn_mfma_i32_32x32x32_i8(af0, wf1, acc[4], 0, 0, 0);
                    acc[5] = __builtin_amdgcn_mfma_i32_32x32x32_i8(af1, wf1, acc[5], 0, 0, 0);
                    acc[6] = __builtin_amdgcn_mfma_i32_32x32x32_i8(af2, wf1, acc[6], 0, 0, 0);
                    acc[7] = __builtin_amdgcn_mfma_i32_32x32x32_i8(af3, wf1, acc[7], 0, 0, 0);
                }
                ++kt;
            }
        }
    }
    asm volatile("s_waitcnt vmcnt(0)" ::: "memory");  // drain the redundant final stage

    if (!CONV1) {
        int pbase = n * HW + y0 * 56;
        #pragma unroll
        for (int ci = 0; ci < 2; ++ci) {
            int co = (wave + ci * 4) * 32 + l31;
            long long ssum = 0, ssq = 0;
            #pragma unroll
            for (int m = 0; m < 4; ++m) {
                v16i a = acc[ci * 4 + m];
                #pragma unroll
                for (int r = 0; r < 16; ++r) {
                    int prow = (r & 3) + ((r >> 2) << 3) + (half << 2);
                    int s = m * 32 + prow;
                    int rr = s >> 6, col = s & 63;
                    if (col < 56) {
                        Cout[(size_t)(pbase + rr * 56 + col) * 256 + co] = a[r];
                        ssum += a[r];
                        ssq  += (long long)a[r] * a[r];
                    }
                }
            }
            ssum += __shfl_xor(ssum, 32);
            ssq  += __shfl_xor(ssq, 32);
            if (half == 0) {
                atomicAdd(&sums[co], (unsigned long long)ssum);
                atomicAdd(&sums[256 + co], (unsigned long long)ssq);
            }
        }
    } else {
        #pragma unroll
        for (int m = 0; m < 4; ++m) {
            int s = m * 32 + l31;
            int rr = s >> 6, col = s & 63;
            if (col < 56) {
                size_t boff = (size_t)n * NCH * HW + (size_t)(y0 + rr) * 56 + col;
                #pragma unroll
                for (int ci = 0; ci < 2; ++ci) {
                    v16i a = acc[ci * 4 + m];
                    #pragma unroll
                    for (int r = 0; r < 16; ++r) {
                        int prow = (r & 3) + ((r >> 2) << 3) + (half << 2);
                        int co = (wave + ci * 4) * 32 + prow;
                        size_t off = boff + (size_t)co * HW;
                        Out[off] = fmaf(s1, (float)a[r], Xin[off]);
                    }
                }
            }
        }
    }
}

__global__ void bn1_finalize(const unsigned long long* __restrict__ sums,
        const float* __restrict__ g, const float* __restrict__ b,
        const float* __restrict__ scale0p, float* __restrict__ A1, float* __restrict__ B1) {
    int c = threadIdx.x;
    double sc0 = (double)*scale0p;
    double S  = (double)(long long)sums[c];
    double S2 = (double)(long long)sums[256 + c];
    double meanS = S / (double)NPIX;
    double varS  = S2 / (double)NPIX - meanS * meanS;
    float meanf = (float)(sc0 * meanS);
    float varf  = (float)(sc0 * sc0 * varS);
    float rstd = (float)(1.0 / sqrt((double)varf + 1e-5));
    float gc = g[c], bc = b[c];
    A1[c] = (float)(sc0 * (double)rstd * (double)gc);
    B1[c] = bc - meanf * rstd * gc;
}

// requantize conv0 output -> padded NHWC int8 (reuses act buffer; halo still zero)
__global__ __launch_bounds__(256) void quant1(const int* __restrict__ Cin,
        const float* __restrict__ A1, const float* __restrict__ B1,
        int8_t* __restrict__ A) {
    int idx = blockIdx.x * 256 + threadIdx.x;
    int e4 = idx * 4;
    if (e4 >= NPIX * 256) return;
    int p = e4 >> 8, c4 = e4 & 255;
    int n = p / HW, r2 = p % HW, y = r2 / 56, xx = r2 % 56;
    const int4 v = *(const int4*)(Cin + e4);
    int vv[4] = {v.x, v.y, v.z, v.w};
    unsigned char qq[4];
    #pragma unroll
    for (int j = 0; j < 4; ++j) {
        float y1 = fmaf((float)vv[j], A1[c4 + j], B1[c4 + j]);
        y1 = fminf(fmaxf(y1, 0.f), 1.f);
        qq[j] = (unsigned char)(int)rintf(y1 * 15.f);
    }
    uchar4 q; q.x = qq[0]; q.y = qq[1]; q.z = qq[2]; q.w = qq[3];
    size_t dst = (((size_t)n * PADH + y + 1) * PADH + xx + 1) * 256 + c4;
    *(uchar4*)(A + dst) = q;
}

extern "C" void kernel_launch(void* const* d_in, const int* in_sizes, int n_in,
                              void* d_out, int out_size, void* d_ws, size_t ws_size,
                              hipStream_t stream) {
    const float* x  = (const float*)d_in[0];
    const float* g0 = (const float*)d_in[1];
    const float* b0 = (const float*)d_in[2];
    const float* w0 = (const float*)d_in[3];
    const float* g1 = (const float*)d_in[4];
    const float* b1 = (const float*)d_in[5];
    const float* w1 = (const float*)d_in[6];
    float* out = (float*)d_out;

    char* ws = (char*)d_ws;
    int8_t* a0 = (int8_t*)(ws + A0_OFF);
    v4i* wp0 = (v4i*)(ws + WP0_OFF);
    v4i* wp1 = (v4i*)(ws + WP1_OFF);
    float* coef = (float*)(ws + COEF_OFF);
    float* A0c = coef;       float* B0c = coef + 256;
    float* A1c = coef + 512; float* B1c = coef + 768;
    float* scale0 = coef + 1024; float* scale1 = coef + 1025;
    unsigned* maxw = (unsigned*)(ws + MAXW_OFF);
    unsigned long long* sums = (unsigned long long*)(ws + SUM1_OFF);
    double2* part = (double2*)(ws + PART_OFF);

    int* c0 = (int*)d_out;   // conv0 raw int32 sums live in d_out until conv1 overwrites it

    hipMemsetAsync(a0, 0, A0_BYTES, stream);
    init_small<<<1, 256, 0, stream>>>(maxw, sums);
    bn0_part<<<4096, 256, 0, stream>>>(x, part);
    bn0_final<<<1, 256, 0, stream>>>(part, g0, b0, A0c, B0c);
    quant0<<<dim3(56, 16), 256, 0, stream>>>(x, A0c, B0c, a0);
    wmax<<<256, 256, 0, stream>>>(w0, maxw);
    wmax<<<256, 256, 0, stream>>>(w1, maxw + 1);
    wpack<<<128, 256, 0, stream>>>(w0, maxw, (int8_t*)wp0, scale0);
    wpack<<<128, 256, 0, stream>>>(w1, maxw + 1, (int8_t*)wp1, scale1);
    conv_mfma<0><<<dim3(28, 16), 256, 0, stream>>>(a0, wp0, c0, sums, nullptr, nullptr, nullptr);
    bn1_finalize<<<1, 256, 0, stream>>>(sums, g1, b1, scale0, A1c, B1c);
    quant1<<<12544, 256, 0, stream>>>(c0, A1c, B1c, a0);
    conv_mfma<1><<<dim3(28, 16), 256, 0, stream>>>(a0, wp1, nullptr, nullptr, scale1, x, out);
}

// Round 4
// 183.396 us; speedup vs baseline: 2.3340x; 1.0523x over previous
//
#include <hip/hip_runtime.h>
#include <stdint.h>
#include <math.h>

typedef int v4i  __attribute__((ext_vector_type(4)));
typedef int v16i __attribute__((ext_vector_type(16)));

#define NIMG 16
#define NCH  256
#define HW   3136          // 56*56
#define NPIX 50176         // 16*3136
#define PADH 58
#define NKT  72            // 2304/32
#define NCOT 8             // 256/32
#define WELEMS 589824      // 256*256*3*3

// workspace layout (bytes)
#define A0_OFF   0
#define A0_BYTES (16*58*58*256)          // padded NHWC int8 acts
#define WP0_OFF  (A0_OFF + A0_BYTES)
#define WP_BYTES (NKT*NCOT*64*16)        // 589,824 packed weight frags
#define WP1_OFF  (WP0_OFF + WP_BYTES)
#define COEF_OFF (WP1_OFF + WP_BYTES)    // floats A0[256] B0[256] A1[256] B1[256] scale0 scale1
#define MAXW_OFF (COEF_OFF + 4352)       // 2 x u32
#define SUM1_OFF (MAXW_OFF + 32)         // 512 x u64
#define PART_OFF (SUM1_OFF + 4096)       // 4096 x double2 (bn0 per-plane partials)

typedef __attribute__((address_space(1))) const unsigned int gu32;
typedef __attribute__((address_space(3))) unsigned int lu32;
__device__ __forceinline__ void gll16(const void* g, void* l) {
    __builtin_amdgcn_global_load_lds((gu32*)g, (lu32*)l, 16, 0, 0);
}

// bn0 stage 1: per-(n,c)-plane sum/sumsq in double, one block per plane.
// block 0 also zero-inits maxw/sums (consumed by later kernels in stream order).
__global__ __launch_bounds__(256) void bn0_part(const float* __restrict__ X,
        double2* __restrict__ part, unsigned* __restrict__ maxw,
        unsigned long long* __restrict__ sums) {
    if (blockIdx.x == 0) {
        int t = threadIdx.x;
        if (t < 2) maxw[t] = 0u;
        for (int i = t; i < 512; i += 256) sums[i] = 0ull;
    }
    int p = blockIdx.x;                    // n*256 + c
    const float4* src = (const float4*)(X + (size_t)p * HW);
    double s = 0.0, s2 = 0.0;
    for (int i = threadIdx.x; i < HW / 4; i += 256) {
        float4 v = src[i];
        s  += (double)v.x + (double)v.y + (double)v.z + (double)v.w;
        s2 += (double)v.x * (double)v.x + (double)v.y * (double)v.y
            + (double)v.z * (double)v.z + (double)v.w * (double)v.w;
    }
    #pragma unroll
    for (int off = 32; off; off >>= 1) {
        s  += __shfl_xor(s, off);
        s2 += __shfl_xor(s2, off);
    }
    __shared__ double sh[8];
    int wave = threadIdx.x >> 6, lane = threadIdx.x & 63;
    if (lane == 0) { sh[wave * 2] = s; sh[wave * 2 + 1] = s2; }
    __syncthreads();
    if (threadIdx.x == 0) {
        double2 o; o.x = sh[0] + sh[2] + sh[4] + sh[6];
        o.y = sh[1] + sh[3] + sh[5] + sh[7];
        part[p] = o;
    }
}

// bn0 stage 2: combine 16 planes per channel (fixed order), emit affine coeffs
__global__ void bn0_final(const double2* __restrict__ part,
        const float* __restrict__ g, const float* __restrict__ b,
        float* __restrict__ A0, float* __restrict__ B0) {
    int c = threadIdx.x;
    double s = 0.0, s2 = 0.0;
    for (int n = 0; n < NIMG; ++n) {
        double2 v = part[n * 256 + c];
        s += v.x; s2 += v.y;
    }
    double mean = s / (double)NPIX;
    double var  = s2 / (double)NPIX - mean * mean;
    float meanf = (float)mean, varf = (float)var;
    float rstd = (float)(1.0 / sqrt((double)varf + 1e-5));
    float gc = g[c], bc = b[c];
    A0[c] = rstd * gc;
    B0[c] = bc - meanf * rstd * gc;
}

// quantize BN0(x) -> padded NHWC int8 via LDS transpose; one block per (n,h)
__global__ __launch_bounds__(256) void quant0(const float* __restrict__ X,
        const float* __restrict__ A0, const float* __restrict__ B0,
        int8_t* __restrict__ Apad) {
    __shared__ int8_t tile[56 * 260];     // stride 260: conflict-free byte columns
    int h = blockIdx.x, n = blockIdx.y;
    int tid = threadIdx.x;
    const float4* src4 = (const float4*)X;
    for (int i = tid; i < 256 * 14; i += 256) {
        int c = i / 14, q = i - c * 14;
        float4 v = src4[((size_t)(n * 256 + c) * HW + h * 56) / 4 + q];
        float ac = A0[c], bc = B0[c];
        float vv[4] = {v.x, v.y, v.z, v.w};
        #pragma unroll
        for (int j = 0; j < 4; ++j) {
            float y = fmaf(vv[j], ac, bc);
            y = fminf(fmaxf(y, 0.f), 1.f);
            tile[(q * 4 + j) * 260 + c] = (int8_t)(int)rintf(y * 15.f);
        }
    }
    __syncthreads();
    unsigned* dst = (unsigned*)(Apad + (((size_t)n * PADH + h + 1) * PADH + 1) * 256);
    for (int i = tid; i < 56 * 64; i += 256) {
        int w = i >> 6, c4 = (i & 63) << 2;
        dst[w * 64 + (c4 >> 2)] = *(const unsigned*)&tile[w * 260 + c4];
    }
}

// both weight tensors' absmax in one launch (blockIdx.y selects tensor)
__global__ __launch_bounds__(256) void wmax2(const float* __restrict__ W0,
        const float* __restrict__ W1, unsigned* __restrict__ out) {
    const float* Wt = blockIdx.y ? W1 : W0;
    __shared__ float sh[256];
    float m = 0.f;
    for (int i = blockIdx.x * 256 + threadIdx.x; i < WELEMS; i += gridDim.x * 256)
        m = fmaxf(m, fabsf(Wt[i]));
    sh[threadIdx.x] = m; __syncthreads();
    for (int o = 128; o > 0; o >>= 1) {
        if (threadIdx.x < o) sh[threadIdx.x] = fmaxf(sh[threadIdx.x], sh[threadIdx.x + o]);
        __syncthreads();
    }
    if (threadIdx.x == 0) atomicMax(&out[blockIdx.y], __float_as_uint(sh[0]));
}

// quantize both weight tensors into per-lane MFMA fragment layout (blockIdx.y selects)
// Wpack[kt][cot][lane][16] ; k = tap*256 + ci ; lane = (k%32/16)*32 + (o%32) ; byte j = k%16
__global__ __launch_bounds__(256) void wpack2(const float* __restrict__ W0,
        const float* __restrict__ W1, const unsigned* __restrict__ maxwBits,
        int8_t* __restrict__ D0, int8_t* __restrict__ D1, float* __restrict__ scales) {
    const float* Wt = blockIdx.y ? W1 : W0;
    int8_t* dst = blockIdx.y ? D1 : D0;
    float maxw = tanhf(__uint_as_float(maxwBits[blockIdx.y]));
    if (blockIdx.x == 0 && threadIdx.x == 0) scales[blockIdx.y] = maxw / 225.f;
    float twoM = 2.f * maxw;
    for (int e = blockIdx.x * 256 + threadIdx.x; e < WELEMS; e += gridDim.x * 256) {
        int o = e / 2304, rem = e % 2304;
        int ci = rem / 9, tap = rem % 9;
        float t = tanhf(Wt[e]);
        float wn = t / twoM + 0.5f;
        int r = (int)rintf(wn * 15.f);
        int q = 2 * r - 15;
        int k = tap * 256 + ci;
        int kt = k >> 5, k5 = k & 31;
        int lane = ((k5 >> 4) << 5) | (o & 31);
        int j = k5 & 15;
        dst[((((size_t)kt * NCOT + (o >> 5)) * 64 + lane) << 4) | j] = (int8_t)q;
    }
}

// wave w stages its own two 1KB weight chunks (cout-tiles c0, c1) of K-step ktn
__device__ __forceinline__ void stageW(const char* wgb, char* ldsbuf,
        int ktn, int c0, int c1, int lane) {
    const char* src = wgb + (size_t)ktn * 8192;
    gll16(src + c0 * 1024 + lane * 16, ldsbuf + c0 * 1024 + lane * 16);
    gll16(src + c1 * 1024 + lane * 16, ldsbuf + c1 * 1024 + lane * 16);
}

// Tiled implicit-GEMM conv. Block: 4 waves, 2 image rows x 256 couts.
// BARRIER-FREE K-loop: each wave stages only the weight chunks IT reads
// (no cross-wave sharing), so vmcnt(2) + program order give all the sync
// the double-buffer needs. Compiler fine-schedules ds_read/MFMA overlap.
template<int CONV1>
__global__ __launch_bounds__(256, 2) void conv_mfma(const int8_t* __restrict__ A,
        const v4i* __restrict__ Wp, int* __restrict__ Cout,
        unsigned long long* __restrict__ sums,
        const float* __restrict__ scale1p, const float* __restrict__ Xin,
        float* __restrict__ Out) {
    __shared__ v4i actT[16 * 233];        // 59.6 KB, read-only after prologue
    __shared__ v4i wbuf[2][512];          // 2 x 8 KB, per-wave chunk ownership
    int tid = threadIdx.x;
    int lane = tid & 63, wave = tid >> 6;
    int rp = blockIdx.x, n = blockIdx.y;
    int y0 = rp * 2;
    int l31 = lane & 31, half = lane >> 5;

    float s1 = 0.f;
    if (CONV1) s1 = *scale1p;

    // ---- act staging: padded rows y0..y0+3, 58 cols, 256 ch -> transposed LDS
    const int8_t* asrc = A + (((size_t)n * PADH + y0) * PADH) * 256;
    for (int i = tid; i < 4 * 58 * 16; i += 256) {
        int rr = i / (58 * 16);
        int rem = i - rr * (58 * 16);
        int px = rem >> 4, hh = rem & 15;
        v4i v = *(const v4i*)(asrc + ((size_t)rr * PADH + px) * 256 + hh * 16);
        actT[hh * 233 + rr * 58 + px] = v;
    }
    __syncthreads();   // drains act loads/stores; actT read-only from here

    int c0 = wave, c1 = wave + 4;
    const char* wgb = (const char*)Wp;
    stageW(wgb, (char*)&wbuf[0][0], 0, c0, c1, lane);   // W[0], own chunks

    // per-lane act pixel indices for the 4 px-tiles
    int pidx[4];
    #pragma unroll
    for (int m = 0; m < 4; ++m) {
        int s = m * 32 + l31;
        int rr = s >> 6, col = s & 63;
        int xx = col < 56 ? col : 55;     // clamp invalid lanes to a safe LDS px
        pidx[m] = (rr + 1) * 58 + xx + 1;
    }

    v16i acc[8] = {};

    int kt = 0;
    #pragma unroll 1
    for (int dyi = 0; dyi < 3; ++dyi) {
        #pragma unroll
        for (int dxi = 0; dxi < 3; ++dxi) {
            int doff = dyi * 58 + dxi - 59;
            #pragma unroll
            for (int kk = 0; kk < 8; ++kk) {
                int ktn = kt + 1; if (ktn > 71) ktn = 71;
                stageW(wgb, (char*)&wbuf[ktn & 1][0], ktn, c0, c1, lane);
                // wait for OWN chunks of W[kt] (2 just-issued remain in flight)
                asm volatile("s_waitcnt vmcnt(2)" ::: "memory");
                const v4i* wb = &wbuf[kt & 1][0];
                int hb = (kk * 2 + half) * 233 + doff;
                v4i wf0 = wb[c0 * 64 + lane];
                v4i wf1 = wb[c1 * 64 + lane];
                v4i af0 = actT[hb + pidx[0]];
                v4i af1 = actT[hb + pidx[1]];
                v4i af2 = actT[hb + pidx[2]];
                v4i af3 = actT[hb + pidx[3]];
                if (CONV1) {
                    acc[0] = __builtin_amdgcn_mfma_i32_32x32x32_i8(wf0, af0, acc[0], 0, 0, 0);
                    acc[1] = __builtin_amdgcn_mfma_i32_32x32x32_i8(wf0, af1, acc[1], 0, 0, 0);
                    acc[2] = __builtin_amdgcn_mfma_i32_32x32x32_i8(wf0, af2, acc[2], 0, 0, 0);
                    acc[3] = __builtin_amdgcn_mfma_i32_32x32x32_i8(wf0, af3, acc[3], 0, 0, 0);
                    acc[4] = __builtin_amdgcn_mfma_i32_32x32x32_i8(wf1, af0, acc[4], 0, 0, 0);
                    acc[5] = __builtin_amdgcn_mfma_i32_32x32x32_i8(wf1, af1, acc[5], 0, 0, 0);
                    acc[6] = __builtin_amdgcn_mfma_i32_32x32x32_i8(wf1, af2, acc[6], 0, 0, 0);
                    acc[7] = __builtin_amdgcn_mfma_i32_32x32x32_i8(wf1, af3, acc[7], 0, 0, 0);
                } else {
                    acc[0] = __builtin_amdgcn_mfma_i32_32x32x32_i8(af0, wf0, acc[0], 0, 0, 0);
                    acc[1] = __builtin_amdgcn_mfma_i32_32x32x32_i8(af1, wf0, acc[1], 0, 0, 0);
                    acc[2] = __builtin_amdgcn_mfma_i32_32x32x32_i8(af2, wf0, acc[2], 0, 0, 0);
                    acc[3] = __builtin_amdgcn_mfma_i32_32x32x32_i8(af3, wf0, acc[3], 0, 0, 0);
                    acc[4] = __builtin_amdgcn_mfma_i32_32x32x32_i8(af0, wf1, acc[4], 0, 0, 0);
                    acc[5] = __builtin_amdgcn_mfma_i32_32x32x32_i8(af1, wf1, acc[5], 0, 0, 0);
                    acc[6] = __builtin_amdgcn_mfma_i32_32x32x32_i8(af2, wf1, acc[6], 0, 0, 0);
                    acc[7] = __builtin_amdgcn_mfma_i32_32x32x32_i8(af3, wf1, acc[7], 0, 0, 0);
                }
                ++kt;
            }
        }
    }
    asm volatile("s_waitcnt vmcnt(0)" ::: "memory");  // drain the redundant final stage

    if (!CONV1) {
        int pbase = n * HW + y0 * 56;
        #pragma unroll
        for (int ci = 0; ci < 2; ++ci) {
            int co = (wave + ci * 4) * 32 + l31;
            long long ssum = 0, ssq = 0;
            #pragma unroll
            for (int m = 0; m < 4; ++m) {
                v16i a = acc[ci * 4 + m];
                #pragma unroll
                for (int r = 0; r < 16; ++r) {
                    int prow = (r & 3) + ((r >> 2) << 3) + (half << 2);
                    int s = m * 32 + prow;
                    int rr = s >> 6, col = s & 63;
                    if (col < 56) {
                        Cout[(size_t)(pbase + rr * 56 + col) * 256 + co] = a[r];
                        ssum += a[r];
                        ssq  += (long long)a[r] * a[r];
                    }
                }
            }
            ssum += __shfl_xor(ssum, 32);
            ssq  += __shfl_xor(ssq, 32);
            if (half == 0) {
                atomicAdd(&sums[co], (unsigned long long)ssum);
                atomicAdd(&sums[256 + co], (unsigned long long)ssq);
            }
        }
    } else {
        #pragma unroll
        for (int m = 0; m < 4; ++m) {
            int s = m * 32 + l31;
            int rr = s >> 6, col = s & 63;
            if (col < 56) {
                size_t boff = (size_t)n * NCH * HW + (size_t)(y0 + rr) * 56 + col;
                #pragma unroll
                for (int ci = 0; ci < 2; ++ci) {
                    v16i a = acc[ci * 4 + m];
                    #pragma unroll
                    for (int r = 0; r < 16; ++r) {
                        int prow = (r & 3) + ((r >> 2) << 3) + (half << 2);
                        int co = (wave + ci * 4) * 32 + prow;
                        size_t off = boff + (size_t)co * HW;
                        Out[off] = fmaf(s1, (float)a[r], Xin[off]);
                    }
                }
            }
        }
    }
}

__global__ void bn1_finalize(const unsigned long long* __restrict__ sums,
        const float* __restrict__ g, const float* __restrict__ b,
        const float* __restrict__ scale0p, float* __restrict__ A1, float* __restrict__ B1) {
    int c = threadIdx.x;
    double sc0 = (double)*scale0p;
    double S  = (double)(long long)sums[c];
    double S2 = (double)(long long)sums[256 + c];
    double meanS = S / (double)NPIX;
    double varS  = S2 / (double)NPIX - meanS * meanS;
    float meanf = (float)(sc0 * meanS);
    float varf  = (float)(sc0 * sc0 * varS);
    float rstd = (float)(1.0 / sqrt((double)varf + 1e-5));
    float gc = g[c], bc = b[c];
    A1[c] = (float)(sc0 * (double)rstd * (double)gc);
    B1[c] = bc - meanf * rstd * gc;
}

// requantize conv0 output -> padded NHWC int8 (reuses act buffer; halo still zero)
__global__ __launch_bounds__(256) void quant1(const int* __restrict__ Cin,
        const float* __restrict__ A1, const float* __restrict__ B1,
        int8_t* __restrict__ A) {
    int idx = blockIdx.x * 256 + threadIdx.x;
    int e4 = idx * 4;
    if (e4 >= NPIX * 256) return;
    int p = e4 >> 8, c4 = e4 & 255;
    int n = p / HW, r2 = p % HW, y = r2 / 56, xx = r2 % 56;
    const int4 v = *(const int4*)(Cin + e4);
    int vv[4] = {v.x, v.y, v.z, v.w};
    unsigned char qq[4];
    #pragma unroll
    for (int j = 0; j < 4; ++j) {
        float y1 = fmaf((float)vv[j], A1[c4 + j], B1[c4 + j]);
        y1 = fminf(fmaxf(y1, 0.f), 1.f);
        qq[j] = (unsigned char)(int)rintf(y1 * 15.f);
    }
    uchar4 q; q.x = qq[0]; q.y = qq[1]; q.z = qq[2]; q.w = qq[3];
    size_t dst = (((size_t)n * PADH + y + 1) * PADH + xx + 1) * 256 + c4;
    *(uchar4*)(A + dst) = q;
}

extern "C" void kernel_launch(void* const* d_in, const int* in_sizes, int n_in,
                              void* d_out, int out_size, void* d_ws, size_t ws_size,
                              hipStream_t stream) {
    const float* x  = (const float*)d_in[0];
    const float* g0 = (const float*)d_in[1];
    const float* b0 = (const float*)d_in[2];
    const float* w0 = (const float*)d_in[3];
    const float* g1 = (const float*)d_in[4];
    const float* b1 = (const float*)d_in[5];
    const float* w1 = (const float*)d_in[6];
    float* out = (float*)d_out;

    char* ws = (char*)d_ws;
    int8_t* a0 = (int8_t*)(ws + A0_OFF);
    v4i* wp0 = (v4i*)(ws + WP0_OFF);
    v4i* wp1 = (v4i*)(ws + WP1_OFF);
    float* coef = (float*)(ws + COEF_OFF);
    float* A0c = coef;       float* B0c = coef + 256;
    float* A1c = coef + 512; float* B1c = coef + 768;
    float* scales = coef + 1024;             // [0]=scale0 [1]=scale1
    unsigned* maxw = (unsigned*)(ws + MAXW_OFF);
    unsigned long long* sums = (unsigned long long*)(ws + SUM1_OFF);
    double2* part = (double2*)(ws + PART_OFF);

    int* c0 = (int*)d_out;   // conv0 raw int32 sums live in d_out until conv1 overwrites it

    hipMemsetAsync(a0, 0, A0_BYTES, stream);
    bn0_part<<<4096, 256, 0, stream>>>(x, part, maxw, sums);
    bn0_final<<<1, 256, 0, stream>>>(part, g0, b0, A0c, B0c);
    quant0<<<dim3(56, 16), 256, 0, stream>>>(x, A0c, B0c, a0);
    wmax2<<<dim3(256, 2), 256, 0, stream>>>(w0, w1, maxw);
    wpack2<<<dim3(128, 2), 256, 0, stream>>>(w0, w1, maxw, (int8_t*)wp0, (int8_t*)wp1, scales);
    conv_mfma<0><<<dim3(28, 16), 256, 0, stream>>>(a0, wp0, c0, sums, nullptr, nullptr, nullptr);
    bn1_finalize<<<1, 256, 0, stream>>>(sums, g1, b1, scales, A1c, B1c);
    quant1<<<12544, 256, 0, stream>>>(c0, A1c, B1c, a0);
    conv_mfma<1><<<dim3(28, 16), 256, 0, stream>>>(a0, wp1, nullptr, nullptr, scales + 1, x, out);
}